// Round 1
// 1867.097 us; speedup vs baseline: 1.0780x; 1.0780x over previous
//
#include <hip/hip_runtime.h>
#include <math.h>
#include <stdint.h>

// Problem constants (match reference)
constexpr int kB = 2, kS = 2048, kD = 1024, kH = 16, kF = 4096, kL = 3;
constexpr int kDK = 64;
constexpr int kQKV = 3 * kD;            // fused QKV width 3072

typedef __attribute__((ext_vector_type(8))) short short8;
typedef __attribute__((ext_vector_type(4))) float floatx4;

// bf16 helpers (RNE pack, shift-unpack)
__device__ inline float bf2f(unsigned short u) {
  union { uint32_t i; float f; } v; v.i = (uint32_t)u << 16; return v.f;
}
__device__ inline unsigned short f2bf(float x) {
  union { float f; uint32_t i; } v; v.f = x;
  uint32_t r = v.i + 0x7fffu + ((v.i >> 16) & 1u);
  return (unsigned short)(r >> 16);
}

// async global->LDS DMA, 16B per lane; LDS dest = wave-uniform base + lane*16
__device__ inline void dma16(const void* g, void* l) {
  __builtin_amdgcn_global_load_lds(
      (const __attribute__((address_space(1))) unsigned int*)g,
      (__attribute__((address_space(3))) unsigned int*)l, 16, 0, 0);
}

// ---------------------------------------------------------------------------
// Embedding: x[b,s,:] = emb[tok]*sqrt(D) + pe[s,:]
// ---------------------------------------------------------------------------
__global__ __launch_bounds__(256) void embed_kernel(
    const int* __restrict__ tokens, const float* __restrict__ emb,
    const float* __restrict__ pe, float* __restrict__ x)
{
  int i = blockIdx.x;
  int s = i & (kS - 1);
  int tok = tokens[i];
  const float4* ep = (const float4*)(emb + (size_t)tok * kD);
  const float4* pp = (const float4*)(pe + (size_t)s * kD);
  float4* xp = (float4*)(x + (size_t)i * kD);
  int t = threadIdx.x;
  float4 e = ep[t], p = pp[t];
  xp[t] = make_float4(e.x*32.0f + p.x, e.y*32.0f + p.y,
                      e.z*32.0f + p.z, e.w*32.0f + p.w);
}

// ---------------------------------------------------------------------------
// LayerNorm (torch-style: Bessel std ddof=1, eps on std) -> fp32 out
// ---------------------------------------------------------------------------
__global__ __launch_bounds__(256) void ln_kernel(
    const float* __restrict__ x, const float* __restrict__ ga,
    const float* __restrict__ gb, float* __restrict__ out)
{
  int row = blockIdx.x;
  int t = threadIdx.x;
  int lane = t & 63, wid = t >> 6;
  const float4* xp = (const float4*)(x + (size_t)row * kD);
  float4 v = xp[t];
  float s = v.x + v.y + v.z + v.w;
  #pragma unroll
  for (int o = 32; o; o >>= 1) s += __shfl_xor(s, o);
  __shared__ float red[4];
  if (lane == 0) red[wid] = s;
  __syncthreads();
  float mean = (red[0] + red[1] + red[2] + red[3]) * (1.0f / 1024.0f);
  float4 d = make_float4(v.x - mean, v.y - mean, v.z - mean, v.w - mean);
  float ss = d.x*d.x + d.y*d.y + d.z*d.z + d.w*d.w;
  #pragma unroll
  for (int o = 32; o; o >>= 1) ss += __shfl_xor(ss, o);
  __syncthreads();
  if (lane == 0) red[wid] = ss;
  __syncthreads();
  float var = (red[0] + red[1] + red[2] + red[3]) * (1.0f / 1023.0f);
  float inv = 1.0f / (sqrtf(var) + 1e-6f);
  float4 a4 = ((const float4*)ga)[t];
  float4 b4 = ((const float4*)gb)[t];
  float4 o4;
  o4.x = a4.x * d.x * inv + b4.x;
  o4.y = a4.y * d.y * inv + b4.y;
  o4.z = a4.z * d.z * inv + b4.z;
  o4.w = a4.w * d.w * inv + b4.w;
  ((float4*)(out + (size_t)row * kD))[t] = o4;
}

// ---------------------------------------------------------------------------
// LayerNorm -> bf16 hi/lo planes (input to split-bf16 MFMA GEMMs)
// ---------------------------------------------------------------------------
__global__ __launch_bounds__(256) void ln_split_kernel(
    const float* __restrict__ x, const float* __restrict__ ga,
    const float* __restrict__ gb, unsigned short* __restrict__ hi,
    unsigned short* __restrict__ lo)
{
  int row = blockIdx.x;
  int t = threadIdx.x;
  int lane = t & 63, wid = t >> 6;
  const float4* xp = (const float4*)(x + (size_t)row * kD);
  float4 v = xp[t];
  float s = v.x + v.y + v.z + v.w;
  #pragma unroll
  for (int o = 32; o; o >>= 1) s += __shfl_xor(s, o);
  __shared__ float red[4];
  if (lane == 0) red[wid] = s;
  __syncthreads();
  float mean = (red[0] + red[1] + red[2] + red[3]) * (1.0f / 1024.0f);
  float4 d = make_float4(v.x - mean, v.y - mean, v.z - mean, v.w - mean);
  float ss = d.x*d.x + d.y*d.y + d.z*d.z + d.w*d.w;
  #pragma unroll
  for (int o = 32; o; o >>= 1) ss += __shfl_xor(ss, o);
  __syncthreads();
  if (lane == 0) red[wid] = ss;
  __syncthreads();
  float var = (red[0] + red[1] + red[2] + red[3]) * (1.0f / 1023.0f);
  float inv = 1.0f / (sqrtf(var) + 1e-6f);
  float4 a4 = ((const float4*)ga)[t];
  float4 b4 = ((const float4*)gb)[t];
  float o0 = a4.x * d.x * inv + b4.x;
  float o1 = a4.y * d.y * inv + b4.y;
  float o2 = a4.z * d.z * inv + b4.z;
  float o3 = a4.w * d.w * inv + b4.w;
  ushort4 h4, l4;
  h4.x = f2bf(o0); l4.x = f2bf(o0 - bf2f(h4.x));
  h4.y = f2bf(o1); l4.y = f2bf(o1 - bf2f(h4.y));
  h4.z = f2bf(o2); l4.z = f2bf(o2 - bf2f(h4.z));
  h4.w = f2bf(o3); l4.w = f2bf(o3 - bf2f(h4.w));
  *(ushort4*)&hi[(size_t)row * kD + 4*t] = h4;
  *(ushort4*)&lo[(size_t)row * kD + 4*t] = l4;
}

// ---------------------------------------------------------------------------
// Weight convert: W[K][N] fp32 -> transposed bf16 hi/lo planes Wt[N][K].
// ---------------------------------------------------------------------------
__global__ __launch_bounds__(256) void wconv_kernel(
    const float* __restrict__ W, unsigned short* __restrict__ hi,
    unsigned short* __restrict__ lo, int K, int N)
{
  __shared__ float tile[64][65];
  int n0 = blockIdx.x * 64, k0 = blockIdx.y * 64;
  int c = threadIdx.x & 63, r0 = threadIdx.x >> 6;
  #pragma unroll
  for (int p = 0; p < 16; ++p) {
    int r = r0 + 4 * p;
    tile[r][c] = W[(size_t)(k0 + r) * N + n0 + c];
  }
  __syncthreads();
  #pragma unroll
  for (int p = 0; p < 16; ++p) {
    int nn = r0 + 4 * p;
    float xv = tile[c][nn];                 // = W[k0+c][n0+nn]
    unsigned short h = f2bf(xv);
    size_t o = (size_t)(n0 + nn) * K + k0 + c;
    hi[o] = h;
    lo[o] = f2bf(xv - bf2f(h));
  }
}

// ---------------------------------------------------------------------------
// Split-bf16 MFMA GEMM v2.  A hi/lo [M][K] bf16; W hi/lo transposed [N][K].
// TERMS=3: Ahi*Whi + Ahi*Wlo + Alo*Whi.  TERMS=2: Ahi*(Whi+Wlo).
// 128x128 tile, BK=32, 4 waves (64x64, 4x4 mfma_16x16x32_bf16).
// Staging via global_load_lds width=16 (async DMA).
// Chunk-XOR swizzle applied on the global address side -> frag ds_read_b128
// hits 8 bank-groups x 2-way = conflict-free.
// OUTMODE 0: fp32 (+resid). 1: relu->bf16 plane. 2: bf16 plane.
// OUTMODE 3: fused-QKV special: cols<2048 -> bf16 qk [M][2048];
//            cols>=2048 -> bf16 V^T [(b*16+h)][dk=64][s=2048] via `resid` ptr.
// ---------------------------------------------------------------------------
template<int TERMS, int OUTMODE>
__global__ __launch_bounds__(256, 3) void mfma_gemm(
    const unsigned short* __restrict__ Ahi, const unsigned short* __restrict__ Alo,
    const unsigned short* __restrict__ Whi, const unsigned short* __restrict__ Wlo,
    const float* __restrict__ bias, const float* __restrict__ resid,
    void* __restrict__ out, int M, int N, int K)
{
  __shared__ unsigned short sAhi[128 * 32];
  __shared__ unsigned short sBhi[128 * 32];
  __shared__ unsigned short sBlo[128 * 32];
  __shared__ unsigned short sAlo[TERMS == 3 ? 128 * 32 : 64];

  int t = threadIdx.x;
  int lane = t & 63, wv = t >> 6;
  int wm = (wv >> 1) * 64, wn = (wv & 1) * 64;
  int lr = lane & 15, lq = lane >> 4;
  int m0 = blockIdx.y * 128, n0 = blockIdx.x * 128;

  // DMA lane mapping: wave-op W covers rows 16W..16W+15, lane l -> row
  // 16W+(l>>2), global chunk (l&3)^s(row), s = ((l>>2)^(l>>4))&3.
  int u = lane >> 2;
  int kq_g = (lane & 3) ^ ((u ^ (u >> 2)) & 3);
  // fragment-read swizzle: s depends only on row mod 16 (= lr)
  int swv = (lr ^ (lr >> 2)) & 3;

  floatx4 acc[4][4];
  #pragma unroll
  for (int i = 0; i < 4; ++i)
    #pragma unroll
    for (int j = 0; j < 4; ++j) acc[i][j] = (floatx4){0.f, 0.f, 0.f, 0.f};

  for (int k0 = 0; k0 < K; k0 += 32) {
    __syncthreads();                         // prev iter's frag readers done
    #pragma unroll
    for (int p = 0; p < 2; ++p) {
      int W = 2 * wv + p;
      size_t ga = (size_t)(m0 + 16 * W + u) * K + k0 + 8 * kq_g;
      size_t gb = (size_t)(n0 + 16 * W + u) * K + k0 + 8 * kq_g;
      dma16(&Ahi[ga], &sAhi[W * 512]);
      if (TERMS == 3) dma16(&Alo[ga], &sAlo[W * 512]);
      dma16(&Whi[gb], &sBhi[W * 512]);
      dma16(&Wlo[gb], &sBlo[W * 512]);
    }
    __syncthreads();                         // drains vmcnt -> DMA visible

    short8 ah[4], bh[4];
    #pragma unroll
    for (int i = 0; i < 4; ++i)
      ah[i] = *(const short8*)&sAhi[(wm + 16*i + lr) * 32 + 8 * (lq ^ swv)];
    #pragma unroll
    for (int j = 0; j < 4; ++j)
      bh[j] = *(const short8*)&sBhi[(wn + 16*j + lr) * 32 + 8 * (lq ^ swv)];
    #pragma unroll
    for (int i = 0; i < 4; ++i)
      #pragma unroll
      for (int j = 0; j < 4; ++j)
        acc[i][j] = __builtin_amdgcn_mfma_f32_16x16x32_bf16(ah[i], bh[j], acc[i][j], 0, 0, 0);

    short8 bl[4];
    #pragma unroll
    for (int j = 0; j < 4; ++j)
      bl[j] = *(const short8*)&sBlo[(wn + 16*j + lr) * 32 + 8 * (lq ^ swv)];
    #pragma unroll
    for (int i = 0; i < 4; ++i)
      #pragma unroll
      for (int j = 0; j < 4; ++j)
        acc[i][j] = __builtin_amdgcn_mfma_f32_16x16x32_bf16(ah[i], bl[j], acc[i][j], 0, 0, 0);

    if (TERMS == 3) {
      short8 al[4];
      #pragma unroll
      for (int i = 0; i < 4; ++i)
        al[i] = *(const short8*)&sAlo[(wm + 16*i + lr) * 32 + 8 * (lq ^ swv)];
      #pragma unroll
      for (int i = 0; i < 4; ++i)
        #pragma unroll
        for (int j = 0; j < 4; ++j)
          acc[i][j] = __builtin_amdgcn_mfma_f32_16x16x32_bf16(al[i], bh[j], acc[i][j], 0, 0, 0);
    }
  }

  if (OUTMODE == 3) {
    // fused-QKV epilogue: Q,K cols -> qk [M][2048]; V cols -> transposed vT.
    unsigned short* qk  = (unsigned short*)out;
    unsigned short* vTp = (unsigned short*)resid;   // aux output via resid slot
    #pragma unroll
    for (int i = 0; i < 4; ++i) {
      #pragma unroll
      for (int j = 0; j < 4; ++j) {
        int col = n0 + wn + 16*j + lr;
        float bv = bias[col];
        int row0 = m0 + wm + 16*i + 4*lq;
        if (col < 2048) {
          #pragma unroll
          for (int r = 0; r < 4; ++r)
            qk[(size_t)(row0 + r) * 2048 + col] = f2bf(acc[i][j][r] + bv);
        } else {
          ushort4 w;
          w.x = f2bf(acc[i][j][0] + bv);
          w.y = f2bf(acc[i][j][1] + bv);
          w.z = f2bf(acc[i][j][2] + bv);
          w.w = f2bf(acc[i][j][3] + bv);
          int bb = row0 >> 11, s0 = row0 & 2047;
          int hh = (col - 2048) >> 6, dk = (col - 2048) & 63;
          *(ushort4*)&vTp[((size_t)((bb << 4) + hh) * 64 + dk) * 2048 + s0] = w;
        }
      }
    }
    return;
  }

  // epilogue: C/D layout col=lane&15, row=(lane>>4)*4+reg
  #pragma unroll
  for (int i = 0; i < 4; ++i) {
    #pragma unroll
    for (int j = 0; j < 4; ++j) {
      int col = n0 + wn + 16*j + lr;
      float bv = bias[col];
      #pragma unroll
      for (int r = 0; r < 4; ++r) {
        int row = m0 + wm + 16*i + 4*lq + r;
        float val = acc[i][j][r] + bv;
        if (OUTMODE == 0) {
          if (resid) val += resid[(size_t)row * N + col];
          ((float*)out)[(size_t)row * N + col] = val;
        } else if (OUTMODE == 1) {
          ((unsigned short*)out)[(size_t)row * N + col] = f2bf(fmaxf(val, 0.f));
        } else {
          ((unsigned short*)out)[(size_t)row * N + col] = f2bf(val);
        }
      }
    }
  }
}

// ---------------------------------------------------------------------------
// MFMA flash attention v2.
//  - Q,K from qk [T][2048] (Q cols 0..1023, K cols 1024..2047), ld = 2048.
//  - V from pre-transposed vT [(b*16+h)][dk=64][s=2048] (GEMM OUTMODE 3):
//    no in-kernel transpose -> no 16-way LDS write conflicts.
//  - All staging via global_load_lds w=16 into linear LDS [row][64], with
//    chunk^=(row&7) swizzle on the GLOBAL side so ds_read_b128 frags are
//    2-way (free).
//  - QBLK=64, 4 waves x 16 q-rows; 33KB LDS -> 4 blocks/CU (16 waves/CU).
//  - grid 1024 blocks, head-minor (bh=bi&31) so one head's 32 q-tiles pin
//    to one XCD -> K/V L2-resident.
// ---------------------------------------------------------------------------
#define ASTR 72

__global__ __launch_bounds__(256, 4) void attn_kernel(
    const unsigned short* __restrict__ QKg, const unsigned short* __restrict__ vT,
    const int* __restrict__ mask, unsigned short* __restrict__ oHi,
    unsigned short* __restrict__ oLo)
{
  __shared__ unsigned short Qs[64 * 64];   // [q][d]  swizzled chunks
  __shared__ unsigned short Ks[64 * 64];   // [k][d]  swizzled chunks
  __shared__ unsigned short Vs[64 * 64];   // [d][k]  swizzled chunks
  __shared__ unsigned short Ps[64 * ASTR]; // [q][k]  padded stride

  int bi = blockIdx.x;
  int bh = bi & 31;                 // head-minor: same head -> same XCD
  int qt = bi >> 5;
  int h = bh & 15, b = bh >> 4;
  int q0 = qt * 64;
  int t = threadIdx.x;
  int lane = t & 63, wv = t >> 6;
  int lr = lane & 15, lq = lane >> 4;
  int wq = wv * 16;

  const size_t qbase = (size_t)b * kS * 2048 + (size_t)h * kDK;
  const size_t kbase = qbase + 1024;
  const size_t vbase = (size_t)(b * kH + h) * 64 * 2048;
  const size_t hout  = (size_t)b * kS * kD + (size_t)h * kDK;

  // stage Q (64 rows x 8 chunks), swizzle on global side
  #pragma unroll
  for (int p = 0; p < 2; ++p) {
    int idx = t + 256 * p;
    int row = idx >> 3, cg = (idx & 7) ^ (row & 7);
    dma16(&QKg[qbase + (size_t)(q0 + row) * 2048 + 8 * cg],
          &Qs[(p * 256 + wv * 64) * 8]);
  }

  floatx4 Oacc[4];
  float m_i[4], l_i[4];
  #pragma unroll
  for (int r = 0; r < 4; ++r) { m_i[r] = -3.0e38f; l_i[r] = 0.0f; }
  #pragma unroll
  for (int j = 0; j < 4; ++j) Oacc[j] = (floatx4){0.f, 0.f, 0.f, 0.f};

  for (int k0 = 0; k0 < kS; k0 += 64) {
    __syncthreads();                      // prev tile's frag readers done
    #pragma unroll
    for (int p = 0; p < 2; ++p) {
      int idx = t + 256 * p;
      int row = idx >> 3, cg = (idx & 7) ^ (row & 7);
      dma16(&QKg[kbase + (size_t)(k0 + row) * 2048 + 8 * cg],
            &Ks[(p * 256 + wv * 64) * 8]);
      dma16(&vT[vbase + (size_t)row * 2048 + k0 + 8 * cg],
            &Vs[(p * 256 + wv * 64) * 8]);
    }
    int mv[4];
    #pragma unroll
    for (int j = 0; j < 4; ++j) mv[j] = mask[b * kS + k0 + 16*j + lr];
    __syncthreads();                      // drains vmcnt -> DMA visible

    floatx4 sac[4];
    #pragma unroll
    for (int j = 0; j < 4; ++j) sac[j] = (floatx4){0.f, 0.f, 0.f, 0.f};
    #pragma unroll
    for (int ks = 0; ks < 2; ++ks) {
      int cs = ((4 * ks + lq) ^ (lr & 7)) * 8;
      short8 af = *(const short8*)&Qs[(wq + lr) * 64 + cs];
      short8 bf[4];
      #pragma unroll
      for (int j = 0; j < 4; ++j)
        bf[j] = *(const short8*)&Ks[(16*j + lr) * 64 + cs];
      #pragma unroll
      for (int j = 0; j < 4; ++j)
        sac[j] = __builtin_amdgcn_mfma_f32_16x16x32_bf16(af, bf[j], sac[j], 0, 0, 0);
    }

    #pragma unroll
    for (int j = 0; j < 4; ++j) {
      #pragma unroll
      for (int r = 0; r < 4; ++r) sac[j][r] *= 0.125f;
      if (mv[j] == 0)
        #pragma unroll
        for (int r = 0; r < 4; ++r) sac[j][r] = -1e9f;
    }

    float alf[4];
    #pragma unroll
    for (int r = 0; r < 4; ++r) {
      float mx = fmaxf(fmaxf(sac[0][r], sac[1][r]),
                       fmaxf(sac[2][r], sac[3][r]));
      #pragma unroll
      for (int o = 1; o < 16; o <<= 1) mx = fmaxf(mx, __shfl_xor(mx, o));
      float newm = fmaxf(m_i[r], mx);
      float rs = 0.0f;
      #pragma unroll
      for (int j = 0; j < 4; ++j) {
        float e = __expf(sac[j][r] - newm);
        sac[j][r] = e; rs += e;
      }
      #pragma unroll
      for (int o = 1; o < 16; o <<= 1) rs += __shfl_xor(rs, o);
      alf[r] = __expf(m_i[r] - newm);
      l_i[r] = l_i[r] * alf[r] + rs;
      m_i[r] = newm;
    }

    #pragma unroll
    for (int j = 0; j < 4; ++j)
      #pragma unroll
      for (int r = 0; r < 4; ++r)
        Ps[(wq + 4*lq + r) * ASTR + 16*j + lr] = f2bf(sac[j][r]);

    #pragma unroll
    for (int j = 0; j < 4; ++j)
      #pragma unroll
      for (int r = 0; r < 4; ++r) Oacc[j][r] *= alf[r];

    #pragma unroll
    for (int ks = 0; ks < 2; ++ks) {
      int cs = ((4 * ks + lq) ^ (lr & 7)) * 8;
      short8 pa = *(const short8*)&Ps[(wq + lr) * ASTR + 32*ks + 8*lq];
      short8 vb[4];
      #pragma unroll
      for (int j = 0; j < 4; ++j)
        vb[j] = *(const short8*)&Vs[(16*j + lr) * 64 + cs];
      #pragma unroll
      for (int j = 0; j < 4; ++j)
        Oacc[j] = __builtin_amdgcn_mfma_f32_16x16x32_bf16(pa, vb[j], Oacc[j], 0, 0, 0);
    }
  }

  float inv[4];
  #pragma unroll
  for (int r = 0; r < 4; ++r) inv[r] = 1.0f / l_i[r];
  #pragma unroll
  for (int j = 0; j < 4; ++j)
    #pragma unroll
    for (int r = 0; r < 4; ++r) {
      int row = q0 + wq + 4*lq + r;
      float val = Oacc[j][r] * inv[r];
      unsigned short hv = f2bf(val);
      unsigned short lv = f2bf(val - bf2f(hv));
      size_t addr = hout + (size_t)row * kD + 16*j + lr;
      oHi[addr] = hv;
      oLo[addr] = lv;
    }
}

// ---------------------------------------------------------------------------
// Orchestration. Workspace byte layout (<= 96 MiB):
//   x      [ 0,16) fp32
//   hHi    [16,24)   hLo [24,32)                 bf16 activation planes
//   qk     [32,48)  bf16 [T][2048] Q|K           (attention phase)
//   vT     [48,56)  bf16 [32][64][2048] V^T      (attention phase)
//   biasqkv[56,56+12KB) fp32[3072]               (attention phase)
//   fpln   [32,64)  bf16 FFN plane               (FFN phase, aliases qk/vT)
//   Wbuf   [64,96): qkv_hi[64,70) qkv_lo[70,76) so_hi[76,78) so_lo[78,80)
//                   ffn_hi[80,88) ffn_lo[88,96)  (w1 then w2, rotating)
// ---------------------------------------------------------------------------
extern "C" void kernel_launch(void* const* d_in, const int* in_sizes, int n_in,
                              void* d_out, int out_size, void* d_ws, size_t ws_size,
                              hipStream_t stream) {
  const int*   tokens = (const int*)d_in[0];
  const int*   mask   = (const int*)d_in[1];
  const float* emb    = (const float*)d_in[2];
  const float* pe     = (const float*)d_in[3];
  const float* Wq     = (const float*)d_in[4];
  const float* bq     = (const float*)d_in[5];
  const float* Wk     = (const float*)d_in[6];
  const float* bk     = (const float*)d_in[7];
  const float* Wv     = (const float*)d_in[8];
  const float* bv     = (const float*)d_in[9];
  const float* Wo     = (const float*)d_in[10];
  const float* bo     = (const float*)d_in[11];
  const float* w1     = (const float*)d_in[12];
  const float* b1     = (const float*)d_in[13];
  const float* w2     = (const float*)d_in[14];
  const float* b2     = (const float*)d_in[15];
  const float* ln_a   = (const float*)d_in[16];
  const float* ln_b   = (const float*)d_in[17];
  const float* fa     = (const float*)d_in[18];
  const float* fb     = (const float*)d_in[19];
  float* out = (float*)d_out;
  char*  ws  = (char*)d_ws;

  const int T = kB * kS;                       // 4096 rows
  constexpr size_t MB = 1024 * 1024;

  float*          x     = (float*)(ws);
  unsigned short* hHi   = (unsigned short*)(ws + 16 * MB);
  unsigned short* hLo   = (unsigned short*)(ws + 24 * MB);
  unsigned short* qk    = (unsigned short*)(ws + 32 * MB);
  unsigned short* vT    = (unsigned short*)(ws + 48 * MB);
  float*          bqkv  = (float*)(ws + 56 * MB);
  unsigned short* fpln  = (unsigned short*)(ws + 32 * MB);  // aliases qk/vT
  char*           Wbuf  = ws + 64 * MB;

  unsigned short* qkv_hi = (unsigned short*)(Wbuf);            // [3072][1024]
  unsigned short* qkv_lo = (unsigned short*)(Wbuf + 6 * MB);
  unsigned short* so_hi  = (unsigned short*)(Wbuf + 12 * MB);
  unsigned short* so_lo  = (unsigned short*)(Wbuf + 14 * MB);
  unsigned short* ffn_hi = (unsigned short*)(Wbuf + 16 * MB);
  unsigned short* ffn_lo = (unsigned short*)(Wbuf + 24 * MB);

  dim3 blk(256);
  embed_kernel<<<T, blk, 0, stream>>>(tokens, emb, pe, x);

  for (int l = 0; l < kL; ++l) {
    const float* Wql = Wq + (size_t)l * kD * kD;
    const float* Wkl = Wk + (size_t)l * kD * kD;
    const float* Wvl = Wv + (size_t)l * kD * kD;
    const float* Wol = Wo + (size_t)l * kD * kD;
    const float* w1l = w1 + (size_t)l * kD * kF;
    const float* w2l = w2 + (size_t)l * kF * kD;

    // fused QKV weight planes: rows 0..1023 = Wq^T, 1024.. = Wk^T, 2048.. = Wv^T
    wconv_kernel<<<dim3(kD/64, kD/64), blk, 0, stream>>>(
        Wql, qkv_hi,                 qkv_lo,                 kD, kD);
    wconv_kernel<<<dim3(kD/64, kD/64), blk, 0, stream>>>(
        Wkl, qkv_hi + (size_t)kD*kD, qkv_lo + (size_t)kD*kD, kD, kD);
    wconv_kernel<<<dim3(kD/64, kD/64), blk, 0, stream>>>(
        Wvl, qkv_hi + (size_t)2*kD*kD, qkv_lo + (size_t)2*kD*kD, kD, kD);
    wconv_kernel<<<dim3(kD/64, kD/64), blk, 0, stream>>>(Wol, so_hi, so_lo, kD, kD);
    hipMemcpyAsync(bqkv,          bq + (size_t)l*kD, kD*4, hipMemcpyDeviceToDevice, stream);
    hipMemcpyAsync(bqkv + kD,     bk + (size_t)l*kD, kD*4, hipMemcpyDeviceToDevice, stream);
    hipMemcpyAsync(bqkv + 2*kD,   bv + (size_t)l*kD, kD*4, hipMemcpyDeviceToDevice, stream);

    // --- attention sublayer ---
    ln_split_kernel<<<T, blk, 0, stream>>>(x, ln_a + (size_t)l * 2 * kD,
                                           ln_b + (size_t)l * 2 * kD, hHi, hLo);
    mfma_gemm<3,3><<<dim3(kQKV/128, T/128), blk, 0, stream>>>(
        hHi, hLo, qkv_hi, qkv_lo, bqkv, (const float*)vT, qk, T, kQKV, kD);
    attn_kernel<<<kB * kH * (kS / 64), blk, 0, stream>>>(
        qk, vT, mask, hHi, hLo);
    mfma_gemm<3,0><<<dim3(kD/128, T/128), blk, 0, stream>>>(
        hHi, hLo, so_hi, so_lo, bo + (size_t)l * kD, x, x, T, kD, kD);

    // --- feed-forward sublayer ---
    ln_split_kernel<<<T, blk, 0, stream>>>(x, ln_a + (size_t)l * 2 * kD + kD,
                                           ln_b + (size_t)l * 2 * kD + kD, hHi, hLo);
    wconv_kernel<<<dim3(kF/64, kD/64), blk, 0, stream>>>(w1l, ffn_hi, ffn_lo, kD, kF);
    mfma_gemm<3,1><<<dim3(kF/128, T/128), blk, 0, stream>>>(
        hHi, hLo, ffn_hi, ffn_lo, b1 + (size_t)l * kF, nullptr, fpln, T, kF, kD);
    wconv_kernel<<<dim3(kD/64, kF/64), blk, 0, stream>>>(w2l, ffn_hi, ffn_lo, kF, kD);
    mfma_gemm<2,0><<<dim3(kD/128, T/128), blk, 0, stream>>>(
        fpln, nullptr, ffn_hi, ffn_lo, b2 + (size_t)l * kD, x, x, T, kD, kF);
  }

  ln_kernel<<<T, blk, 0, stream>>>(x, fa, fb, out);
}

// Round 2
// 1731.763 us; speedup vs baseline: 1.1622x; 1.0781x over previous
//
#include <hip/hip_runtime.h>
#include <math.h>
#include <stdint.h>

// Problem constants (match reference)
constexpr int kB = 2, kS = 2048, kD = 1024, kH = 16, kF = 4096, kL = 3;
constexpr int kDK = 64;
constexpr int kQKV = 3 * kD;            // fused QKV width 3072

typedef __attribute__((ext_vector_type(8))) short short8;
typedef __attribute__((ext_vector_type(4))) float floatx4;

// bf16 helpers (RNE pack, shift-unpack)
__device__ inline float bf2f(unsigned short u) {
  union { uint32_t i; float f; } v; v.i = (uint32_t)u << 16; return v.f;
}
__device__ inline unsigned short f2bf(float x) {
  union { float f; uint32_t i; } v; v.f = x;
  uint32_t r = v.i + 0x7fffu + ((v.i >> 16) & 1u);
  return (unsigned short)(r >> 16);
}

// async global->LDS DMA, 16B per lane; LDS dest = wave-uniform base + lane*16
__device__ inline void dma16(const void* g, void* l) {
  __builtin_amdgcn_global_load_lds(
      (const __attribute__((address_space(1))) unsigned int*)g,
      (__attribute__((address_space(3))) unsigned int*)l, 16, 0, 0);
}

// ---------------------------------------------------------------------------
// Embedding: x[b,s,:] = emb[tok]*sqrt(D) + pe[s,:]
// ---------------------------------------------------------------------------
__global__ __launch_bounds__(256) void embed_kernel(
    const int* __restrict__ tokens, const float* __restrict__ emb,
    const float* __restrict__ pe, float* __restrict__ x)
{
  int i = blockIdx.x;
  int s = i & (kS - 1);
  int tok = tokens[i];
  const float4* ep = (const float4*)(emb + (size_t)tok * kD);
  const float4* pp = (const float4*)(pe + (size_t)s * kD);
  float4* xp = (float4*)(x + (size_t)i * kD);
  int t = threadIdx.x;
  float4 e = ep[t], p = pp[t];
  xp[t] = make_float4(e.x*32.0f + p.x, e.y*32.0f + p.y,
                      e.z*32.0f + p.z, e.w*32.0f + p.w);
}

// ---------------------------------------------------------------------------
// LayerNorm (torch-style: Bessel std ddof=1, eps on std) -> fp32 out
// ---------------------------------------------------------------------------
__global__ __launch_bounds__(256) void ln_kernel(
    const float* __restrict__ x, const float* __restrict__ ga,
    const float* __restrict__ gb, float* __restrict__ out)
{
  int row = blockIdx.x;
  int t = threadIdx.x;
  int lane = t & 63, wid = t >> 6;
  const float4* xp = (const float4*)(x + (size_t)row * kD);
  float4 v = xp[t];
  float s = v.x + v.y + v.z + v.w;
  #pragma unroll
  for (int o = 32; o; o >>= 1) s += __shfl_xor(s, o);
  __shared__ float red[4];
  if (lane == 0) red[wid] = s;
  __syncthreads();
  float mean = (red[0] + red[1] + red[2] + red[3]) * (1.0f / 1024.0f);
  float4 d = make_float4(v.x - mean, v.y - mean, v.z - mean, v.w - mean);
  float ss = d.x*d.x + d.y*d.y + d.z*d.z + d.w*d.w;
  #pragma unroll
  for (int o = 32; o; o >>= 1) ss += __shfl_xor(ss, o);
  __syncthreads();
  if (lane == 0) red[wid] = ss;
  __syncthreads();
  float var = (red[0] + red[1] + red[2] + red[3]) * (1.0f / 1023.0f);
  float inv = 1.0f / (sqrtf(var) + 1e-6f);
  float4 a4 = ((const float4*)ga)[t];
  float4 b4 = ((const float4*)gb)[t];
  float4 o4;
  o4.x = a4.x * d.x * inv + b4.x;
  o4.y = a4.y * d.y * inv + b4.y;
  o4.z = a4.z * d.z * inv + b4.z;
  o4.w = a4.w * d.w * inv + b4.w;
  ((float4*)(out + (size_t)row * kD))[t] = o4;
}

// ---------------------------------------------------------------------------
// LayerNorm -> bf16 hi/lo planes (input to split-bf16 MFMA GEMMs)
// ---------------------------------------------------------------------------
__global__ __launch_bounds__(256) void ln_split_kernel(
    const float* __restrict__ x, const float* __restrict__ ga,
    const float* __restrict__ gb, unsigned short* __restrict__ hi,
    unsigned short* __restrict__ lo)
{
  int row = blockIdx.x;
  int t = threadIdx.x;
  int lane = t & 63, wid = t >> 6;
  const float4* xp = (const float4*)(x + (size_t)row * kD);
  float4 v = xp[t];
  float s = v.x + v.y + v.z + v.w;
  #pragma unroll
  for (int o = 32; o; o >>= 1) s += __shfl_xor(s, o);
  __shared__ float red[4];
  if (lane == 0) red[wid] = s;
  __syncthreads();
  float mean = (red[0] + red[1] + red[2] + red[3]) * (1.0f / 1024.0f);
  float4 d = make_float4(v.x - mean, v.y - mean, v.z - mean, v.w - mean);
  float ss = d.x*d.x + d.y*d.y + d.z*d.z + d.w*d.w;
  #pragma unroll
  for (int o = 32; o; o >>= 1) ss += __shfl_xor(ss, o);
  __syncthreads();
  if (lane == 0) red[wid] = ss;
  __syncthreads();
  float var = (red[0] + red[1] + red[2] + red[3]) * (1.0f / 1023.0f);
  float inv = 1.0f / (sqrtf(var) + 1e-6f);
  float4 a4 = ((const float4*)ga)[t];
  float4 b4 = ((const float4*)gb)[t];
  float o0 = a4.x * d.x * inv + b4.x;
  float o1 = a4.y * d.y * inv + b4.y;
  float o2 = a4.z * d.z * inv + b4.z;
  float o3 = a4.w * d.w * inv + b4.w;
  ushort4 h4, l4;
  h4.x = f2bf(o0); l4.x = f2bf(o0 - bf2f(h4.x));
  h4.y = f2bf(o1); l4.y = f2bf(o1 - bf2f(h4.y));
  h4.z = f2bf(o2); l4.z = f2bf(o2 - bf2f(h4.z));
  h4.w = f2bf(o3); l4.w = f2bf(o3 - bf2f(h4.w));
  *(ushort4*)&hi[(size_t)row * kD + 4*t] = h4;
  *(ushort4*)&lo[(size_t)row * kD + 4*t] = l4;
}

// ---------------------------------------------------------------------------
// Weight convert: W[K][N] fp32 -> transposed bf16 hi/lo planes Wt[N][K].
// ---------------------------------------------------------------------------
__global__ __launch_bounds__(256) void wconv_kernel(
    const float* __restrict__ W, unsigned short* __restrict__ hi,
    unsigned short* __restrict__ lo, int K, int N)
{
  __shared__ float tile[64][65];
  int n0 = blockIdx.x * 64, k0 = blockIdx.y * 64;
  int c = threadIdx.x & 63, r0 = threadIdx.x >> 6;
  #pragma unroll
  for (int p = 0; p < 16; ++p) {
    int r = r0 + 4 * p;
    tile[r][c] = W[(size_t)(k0 + r) * N + n0 + c];
  }
  __syncthreads();
  #pragma unroll
  for (int p = 0; p < 16; ++p) {
    int nn = r0 + 4 * p;
    float xv = tile[c][nn];                 // = W[k0+c][n0+nn]
    unsigned short h = f2bf(xv);
    size_t o = (size_t)(n0 + nn) * K + k0 + c;
    hi[o] = h;
    lo[o] = f2bf(xv - bf2f(h));
  }
}

// ---------------------------------------------------------------------------
// Split-bf16 MFMA GEMM v3.  A hi/lo [M][K] bf16; W hi/lo transposed [N][K].
// TERMS=3: Ahi*Whi + Ahi*Wlo + Alo*Whi.  TERMS=2: Ahi*(Whi+Wlo).
// BN=128: 128x128 tile, 4 waves of 64x64 (4x4 frags).
// BN=64:  128x64 tile,  4 waves of 64x32 (4x2 frags) — for narrow-N GEMMs
//         (N=1024): doubles the grid (512 blocks -> 2 blocks/CU) so the
//         vmcnt-drain barrier stall is hidden by cross-block overlap.
// Staging via global_load_lds width=16 (async DMA).
// Chunk-XOR swizzle applied on the global address side -> frag ds_read_b128
// hits 8 bank-groups x 2-way = conflict-free.
// OUTMODE 0: fp32 (+resid). 1: relu->bf16 plane. 2: bf16 plane.
// OUTMODE 3: fused-QKV special: cols<2048 -> bf16 qk [M][2048];
//            cols>=2048 -> bf16 V^T [(b*16+h)][dk=64][s=2048] via `resid` ptr.
// ---------------------------------------------------------------------------
template<int TERMS, int OUTMODE, int BN>
__global__ __launch_bounds__(256, 3) void mfma_gemm(
    const unsigned short* __restrict__ Ahi, const unsigned short* __restrict__ Alo,
    const unsigned short* __restrict__ Whi, const unsigned short* __restrict__ Wlo,
    const float* __restrict__ bias, const float* __restrict__ resid,
    void* __restrict__ out, int M, int N, int K)
{
  constexpr int NJ = (BN == 128) ? 4 : 2;   // N-frags per wave

  __shared__ unsigned short sAhi[128 * 32];
  __shared__ unsigned short sBhi[BN * 32];
  __shared__ unsigned short sBlo[BN * 32];
  __shared__ unsigned short sAlo[TERMS == 3 ? 128 * 32 : 64];

  int t = threadIdx.x;
  int lane = t & 63, wv = t >> 6;
  int wm, wn;
  if (BN == 128) { wm = (wv >> 1) * 64; wn = (wv & 1) * 64; }
  else           { wm = (wv & 1) * 64;  wn = (wv >> 1) * 32; }
  int lr = lane & 15, lq = lane >> 4;
  int m0 = blockIdx.y * 128, n0 = blockIdx.x * BN;

  // DMA lane mapping: wave-op W covers rows 16W..16W+15, lane l -> row
  // 16W+(l>>2), global chunk (l&3)^s(row), s = ((l>>2)^(l>>4))&3.
  int u = lane >> 2;
  int kq_g = (lane & 3) ^ ((u ^ (u >> 2)) & 3);
  // fragment-read swizzle: s depends only on row mod 16 (= lr)
  int swv = (lr ^ (lr >> 2)) & 3;

  floatx4 acc[4][NJ];
  #pragma unroll
  for (int i = 0; i < 4; ++i)
    #pragma unroll
    for (int j = 0; j < NJ; ++j) acc[i][j] = (floatx4){0.f, 0.f, 0.f, 0.f};

  for (int k0 = 0; k0 < K; k0 += 32) {
    __syncthreads();                         // prev iter's frag readers done
    #pragma unroll
    for (int p = 0; p < 2; ++p) {
      int W = 2 * wv + p;
      size_t ga = (size_t)(m0 + 16 * W + u) * K + k0 + 8 * kq_g;
      dma16(&Ahi[ga], &sAhi[W * 512]);
      if (TERMS == 3) dma16(&Alo[ga], &sAlo[W * 512]);
    }
    if (BN == 128) {
      #pragma unroll
      for (int p = 0; p < 2; ++p) {
        int W = 2 * wv + p;
        size_t gb = (size_t)(n0 + 16 * W + u) * K + k0 + 8 * kq_g;
        dma16(&Whi[gb], &sBhi[W * 512]);
        dma16(&Wlo[gb], &sBlo[W * 512]);
      }
    } else {
      int W = wv;
      size_t gb = (size_t)(n0 + 16 * W + u) * K + k0 + 8 * kq_g;
      dma16(&Whi[gb], &sBhi[W * 512]);
      dma16(&Wlo[gb], &sBlo[W * 512]);
    }
    __syncthreads();                         // drains vmcnt -> DMA visible

    short8 ah[4], bh[NJ];
    #pragma unroll
    for (int i = 0; i < 4; ++i)
      ah[i] = *(const short8*)&sAhi[(wm + 16*i + lr) * 32 + 8 * (lq ^ swv)];
    #pragma unroll
    for (int j = 0; j < NJ; ++j)
      bh[j] = *(const short8*)&sBhi[(wn + 16*j + lr) * 32 + 8 * (lq ^ swv)];
    #pragma unroll
    for (int i = 0; i < 4; ++i)
      #pragma unroll
      for (int j = 0; j < NJ; ++j)
        acc[i][j] = __builtin_amdgcn_mfma_f32_16x16x32_bf16(ah[i], bh[j], acc[i][j], 0, 0, 0);

    short8 bl[NJ];
    #pragma unroll
    for (int j = 0; j < NJ; ++j)
      bl[j] = *(const short8*)&sBlo[(wn + 16*j + lr) * 32 + 8 * (lq ^ swv)];
    #pragma unroll
    for (int i = 0; i < 4; ++i)
      #pragma unroll
      for (int j = 0; j < NJ; ++j)
        acc[i][j] = __builtin_amdgcn_mfma_f32_16x16x32_bf16(ah[i], bl[j], acc[i][j], 0, 0, 0);

    if (TERMS == 3) {
      short8 al[4];
      #pragma unroll
      for (int i = 0; i < 4; ++i)
        al[i] = *(const short8*)&sAlo[(wm + 16*i + lr) * 32 + 8 * (lq ^ swv)];
      #pragma unroll
      for (int i = 0; i < 4; ++i)
        #pragma unroll
        for (int j = 0; j < NJ; ++j)
          acc[i][j] = __builtin_amdgcn_mfma_f32_16x16x32_bf16(al[i], bh[j], acc[i][j], 0, 0, 0);
    }
  }

  if (OUTMODE == 3) {
    // fused-QKV epilogue: Q,K cols -> qk [M][2048]; V cols -> transposed vT.
    unsigned short* qk  = (unsigned short*)out;
    unsigned short* vTp = (unsigned short*)resid;   // aux output via resid slot
    #pragma unroll
    for (int i = 0; i < 4; ++i) {
      #pragma unroll
      for (int j = 0; j < NJ; ++j) {
        int col = n0 + wn + 16*j + lr;
        float bv = bias[col];
        int row0 = m0 + wm + 16*i + 4*lq;
        if (col < 2048) {
          #pragma unroll
          for (int r = 0; r < 4; ++r)
            qk[(size_t)(row0 + r) * 2048 + col] = f2bf(acc[i][j][r] + bv);
        } else {
          ushort4 w;
          w.x = f2bf(acc[i][j][0] + bv);
          w.y = f2bf(acc[i][j][1] + bv);
          w.z = f2bf(acc[i][j][2] + bv);
          w.w = f2bf(acc[i][j][3] + bv);
          int bb = row0 >> 11, s0 = row0 & 2047;
          int hh = (col - 2048) >> 6, dk = (col - 2048) & 63;
          *(ushort4*)&vTp[((size_t)((bb << 4) + hh) * 64 + dk) * 2048 + s0] = w;
        }
      }
    }
    return;
  }

  // epilogue: C/D layout col=lane&15, row=(lane>>4)*4+reg
  #pragma unroll
  for (int i = 0; i < 4; ++i) {
    #pragma unroll
    for (int j = 0; j < NJ; ++j) {
      int col = n0 + wn + 16*j + lr;
      float bv = bias[col];
      #pragma unroll
      for (int r = 0; r < 4; ++r) {
        int row = m0 + wm + 16*i + 4*lq + r;
        float val = acc[i][j][r] + bv;
        if (OUTMODE == 0) {
          if (resid) val += resid[(size_t)row * N + col];
          ((float*)out)[(size_t)row * N + col] = val;
        } else if (OUTMODE == 1) {
          ((unsigned short*)out)[(size_t)row * N + col] = f2bf(fmaxf(val, 0.f));
        } else {
          ((unsigned short*)out)[(size_t)row * N + col] = f2bf(val);
        }
      }
    }
  }
}

// ---------------------------------------------------------------------------
// MFMA flash attention v2.
//  - Q,K from qk [T][2048] (Q cols 0..1023, K cols 1024..2047), ld = 2048.
//  - V from pre-transposed vT [(b*16+h)][dk=64][s=2048] (GEMM OUTMODE 3):
//    no in-kernel transpose -> no 16-way LDS write conflicts.
//  - All staging via global_load_lds w=16 into linear LDS [row][64], with
//    chunk^=(row&7) swizzle on the GLOBAL side so ds_read_b128 frags are
//    2-way (free).
//  - QBLK=64, 4 waves x 16 q-rows; 33KB LDS -> 4 blocks/CU (16 waves/CU).
//  - grid 1024 blocks, head-minor (bh=bi&31) so one head's 32 q-tiles pin
//    to one XCD -> K/V L2-resident.
// ---------------------------------------------------------------------------
#define ASTR 72

__global__ __launch_bounds__(256, 4) void attn_kernel(
    const unsigned short* __restrict__ QKg, const unsigned short* __restrict__ vT,
    const int* __restrict__ mask, unsigned short* __restrict__ oHi,
    unsigned short* __restrict__ oLo)
{
  __shared__ unsigned short Qs[64 * 64];   // [q][d]  swizzled chunks
  __shared__ unsigned short Ks[64 * 64];   // [k][d]  swizzled chunks
  __shared__ unsigned short Vs[64 * 64];   // [d][k]  swizzled chunks
  __shared__ unsigned short Ps[64 * ASTR]; // [q][k]  padded stride

  int bi = blockIdx.x;
  int bh = bi & 31;                 // head-minor: same head -> same XCD
  int qt = bi >> 5;
  int h = bh & 15, b = bh >> 4;
  int q0 = qt * 64;
  int t = threadIdx.x;
  int lane = t & 63, wv = t >> 6;
  int lr = lane & 15, lq = lane >> 4;
  int wq = wv * 16;

  const size_t qbase = (size_t)b * kS * 2048 + (size_t)h * kDK;
  const size_t kbase = qbase + 1024;
  const size_t vbase = (size_t)(b * kH + h) * 64 * 2048;
  const size_t hout  = (size_t)b * kS * kD + (size_t)h * kDK;

  // stage Q (64 rows x 8 chunks), swizzle on global side
  #pragma unroll
  for (int p = 0; p < 2; ++p) {
    int idx = t + 256 * p;
    int row = idx >> 3, cg = (idx & 7) ^ (row & 7);
    dma16(&QKg[qbase + (size_t)(q0 + row) * 2048 + 8 * cg],
          &Qs[(p * 256 + wv * 64) * 8]);
  }

  floatx4 Oacc[4];
  float m_i[4], l_i[4];
  #pragma unroll
  for (int r = 0; r < 4; ++r) { m_i[r] = -3.0e38f; l_i[r] = 0.0f; }
  #pragma unroll
  for (int j = 0; j < 4; ++j) Oacc[j] = (floatx4){0.f, 0.f, 0.f, 0.f};

  for (int k0 = 0; k0 < kS; k0 += 64) {
    __syncthreads();                      // prev tile's frag readers done
    #pragma unroll
    for (int p = 0; p < 2; ++p) {
      int idx = t + 256 * p;
      int row = idx >> 3, cg = (idx & 7) ^ (row & 7);
      dma16(&QKg[kbase + (size_t)(k0 + row) * 2048 + 8 * cg],
            &Ks[(p * 256 + wv * 64) * 8]);
      dma16(&vT[vbase + (size_t)row * 2048 + k0 + 8 * cg],
            &Vs[(p * 256 + wv * 64) * 8]);
    }
    int mv[4];
    #pragma unroll
    for (int j = 0; j < 4; ++j) mv[j] = mask[b * kS + k0 + 16*j + lr];
    __syncthreads();                      // drains vmcnt -> DMA visible

    floatx4 sac[4];
    #pragma unroll
    for (int j = 0; j < 4; ++j) sac[j] = (floatx4){0.f, 0.f, 0.f, 0.f};
    #pragma unroll
    for (int ks = 0; ks < 2; ++ks) {
      int cs = ((4 * ks + lq) ^ (lr & 7)) * 8;
      short8 af = *(const short8*)&Qs[(wq + lr) * 64 + cs];
      short8 bf[4];
      #pragma unroll
      for (int j = 0; j < 4; ++j)
        bf[j] = *(const short8*)&Ks[(16*j + lr) * 64 + cs];
      #pragma unroll
      for (int j = 0; j < 4; ++j)
        sac[j] = __builtin_amdgcn_mfma_f32_16x16x32_bf16(af, bf[j], sac[j], 0, 0, 0);
    }

    #pragma unroll
    for (int j = 0; j < 4; ++j) {
      #pragma unroll
      for (int r = 0; r < 4; ++r) sac[j][r] *= 0.125f;
      if (mv[j] == 0)
        #pragma unroll
        for (int r = 0; r < 4; ++r) sac[j][r] = -1e9f;
    }

    float alf[4];
    #pragma unroll
    for (int r = 0; r < 4; ++r) {
      float mx = fmaxf(fmaxf(sac[0][r], sac[1][r]),
                       fmaxf(sac[2][r], sac[3][r]));
      #pragma unroll
      for (int o = 1; o < 16; o <<= 1) mx = fmaxf(mx, __shfl_xor(mx, o));
      float newm = fmaxf(m_i[r], mx);
      float rs = 0.0f;
      #pragma unroll
      for (int j = 0; j < 4; ++j) {
        float e = __expf(sac[j][r] - newm);
        sac[j][r] = e; rs += e;
      }
      #pragma unroll
      for (int o = 1; o < 16; o <<= 1) rs += __shfl_xor(rs, o);
      alf[r] = __expf(m_i[r] - newm);
      l_i[r] = l_i[r] * alf[r] + rs;
      m_i[r] = newm;
    }

    #pragma unroll
    for (int j = 0; j < 4; ++j)
      #pragma unroll
      for (int r = 0; r < 4; ++r)
        Ps[(wq + 4*lq + r) * ASTR + 16*j + lr] = f2bf(sac[j][r]);

    #pragma unroll
    for (int j = 0; j < 4; ++j)
      #pragma unroll
      for (int r = 0; r < 4; ++r) Oacc[j][r] *= alf[r];

    #pragma unroll
    for (int ks = 0; ks < 2; ++ks) {
      int cs = ((4 * ks + lq) ^ (lr & 7)) * 8;
      short8 pa = *(const short8*)&Ps[(wq + lr) * ASTR + 32*ks + 8*lq];
      short8 vb[4];
      #pragma unroll
      for (int j = 0; j < 4; ++j)
        vb[j] = *(const short8*)&Vs[(16*j + lr) * 64 + cs];
      #pragma unroll
      for (int j = 0; j < 4; ++j)
        Oacc[j] = __builtin_amdgcn_mfma_f32_16x16x32_bf16(pa, vb[j], Oacc[j], 0, 0, 0);
    }
  }

  float inv[4];
  #pragma unroll
  for (int r = 0; r < 4; ++r) inv[r] = 1.0f / l_i[r];
  #pragma unroll
  for (int j = 0; j < 4; ++j)
    #pragma unroll
    for (int r = 0; r < 4; ++r) {
      int row = q0 + wq + 4*lq + r;
      float val = Oacc[j][r] * inv[r];
      unsigned short hv = f2bf(val);
      unsigned short lv = f2bf(val - bf2f(hv));
      size_t addr = hout + (size_t)row * kD + 16*j + lr;
      oHi[addr] = hv;
      oLo[addr] = lv;
    }
}

// ---------------------------------------------------------------------------
// Orchestration. Workspace byte layout (<= 96 MiB):
//   x      [ 0,16) fp32
//   hHi    [16,24)   hLo [24,32)                 bf16 activation planes
//   qk     [32,48)  bf16 [T][2048] Q|K           (attention phase)
//   vT     [48,56)  bf16 [32][64][2048] V^T      (attention phase)
//   biasqkv[56,56+12KB) fp32[3072]               (attention phase)
//   fpln   [32,64)  bf16 FFN plane               (FFN phase, aliases qk/vT)
//   Wbuf   [64,96): qkv_hi[64,70) qkv_lo[70,76) so_hi[76,78) so_lo[78,80)
//                   ffn_hi[80,88) ffn_lo[88,96)  (w1 then w2, rotating)
// ---------------------------------------------------------------------------
extern "C" void kernel_launch(void* const* d_in, const int* in_sizes, int n_in,
                              void* d_out, int out_size, void* d_ws, size_t ws_size,
                              hipStream_t stream) {
  const int*   tokens = (const int*)d_in[0];
  const int*   mask   = (const int*)d_in[1];
  const float* emb    = (const float*)d_in[2];
  const float* pe     = (const float*)d_in[3];
  const float* Wq     = (const float*)d_in[4];
  const float* bq     = (const float*)d_in[5];
  const float* Wk     = (const float*)d_in[6];
  const float* bk     = (const float*)d_in[7];
  const float* Wv     = (const float*)d_in[8];
  const float* bv     = (const float*)d_in[9];
  const float* Wo     = (const float*)d_in[10];
  const float* bo     = (const float*)d_in[11];
  const float* w1     = (const float*)d_in[12];
  const float* b1     = (const float*)d_in[13];
  const float* w2     = (const float*)d_in[14];
  const float* b2     = (const float*)d_in[15];
  const float* ln_a   = (const float*)d_in[16];
  const float* ln_b   = (const float*)d_in[17];
  const float* fa     = (const float*)d_in[18];
  const float* fb     = (const float*)d_in[19];
  float* out = (float*)d_out;
  char*  ws  = (char*)d_ws;

  const int T = kB * kS;                       // 4096 rows
  constexpr size_t MB = 1024 * 1024;

  float*          x     = (float*)(ws);
  unsigned short* hHi   = (unsigned short*)(ws + 16 * MB);
  unsigned short* hLo   = (unsigned short*)(ws + 24 * MB);
  unsigned short* qk    = (unsigned short*)(ws + 32 * MB);
  unsigned short* vT    = (unsigned short*)(ws + 48 * MB);
  float*          bqkv  = (float*)(ws + 56 * MB);
  unsigned short* fpln  = (unsigned short*)(ws + 32 * MB);  // aliases qk/vT
  char*           Wbuf  = ws + 64 * MB;

  unsigned short* qkv_hi = (unsigned short*)(Wbuf);            // [3072][1024]
  unsigned short* qkv_lo = (unsigned short*)(Wbuf + 6 * MB);
  unsigned short* so_hi  = (unsigned short*)(Wbuf + 12 * MB);
  unsigned short* so_lo  = (unsigned short*)(Wbuf + 14 * MB);
  unsigned short* ffn_hi = (unsigned short*)(Wbuf + 16 * MB);
  unsigned short* ffn_lo = (unsigned short*)(Wbuf + 24 * MB);

  dim3 blk(256);
  embed_kernel<<<T, blk, 0, stream>>>(tokens, emb, pe, x);

  for (int l = 0; l < kL; ++l) {
    const float* Wql = Wq + (size_t)l * kD * kD;
    const float* Wkl = Wk + (size_t)l * kD * kD;
    const float* Wvl = Wv + (size_t)l * kD * kD;
    const float* Wol = Wo + (size_t)l * kD * kD;
    const float* w1l = w1 + (size_t)l * kD * kF;
    const float* w2l = w2 + (size_t)l * kF * kD;

    // fused QKV weight planes: rows 0..1023 = Wq^T, 1024.. = Wk^T, 2048.. = Wv^T
    wconv_kernel<<<dim3(kD/64, kD/64), blk, 0, stream>>>(
        Wql, qkv_hi,                 qkv_lo,                 kD, kD);
    wconv_kernel<<<dim3(kD/64, kD/64), blk, 0, stream>>>(
        Wkl, qkv_hi + (size_t)kD*kD, qkv_lo + (size_t)kD*kD, kD, kD);
    wconv_kernel<<<dim3(kD/64, kD/64), blk, 0, stream>>>(
        Wvl, qkv_hi + (size_t)2*kD*kD, qkv_lo + (size_t)2*kD*kD, kD, kD);
    wconv_kernel<<<dim3(kD/64, kD/64), blk, 0, stream>>>(Wol, so_hi, so_lo, kD, kD);
    hipMemcpyAsync(bqkv,          bq + (size_t)l*kD, kD*4, hipMemcpyDeviceToDevice, stream);
    hipMemcpyAsync(bqkv + kD,     bk + (size_t)l*kD, kD*4, hipMemcpyDeviceToDevice, stream);
    hipMemcpyAsync(bqkv + 2*kD,   bv + (size_t)l*kD, kD*4, hipMemcpyDeviceToDevice, stream);

    // --- attention sublayer ---
    ln_split_kernel<<<T, blk, 0, stream>>>(x, ln_a + (size_t)l * 2 * kD,
                                           ln_b + (size_t)l * 2 * kD, hHi, hLo);
    mfma_gemm<3,3,128><<<dim3(kQKV/128, T/128), blk, 0, stream>>>(
        hHi, hLo, qkv_hi, qkv_lo, bqkv, (const float*)vT, qk, T, kQKV, kD);
    attn_kernel<<<kB * kH * (kS / 64), blk, 0, stream>>>(
        qk, vT, mask, hHi, hLo);
    mfma_gemm<3,0,64><<<dim3(kD/64, T/128), blk, 0, stream>>>(
        hHi, hLo, so_hi, so_lo, bo + (size_t)l * kD, x, x, T, kD, kD);

    // --- feed-forward sublayer ---
    ln_split_kernel<<<T, blk, 0, stream>>>(x, ln_a + (size_t)l * 2 * kD + kD,
                                           ln_b + (size_t)l * 2 * kD + kD, hHi, hLo);
    wconv_kernel<<<dim3(kF/64, kD/64), blk, 0, stream>>>(w1l, ffn_hi, ffn_lo, kD, kF);
    mfma_gemm<3,1,128><<<dim3(kF/128, T/128), blk, 0, stream>>>(
        hHi, hLo, ffn_hi, ffn_lo, b1 + (size_t)l * kF, nullptr, fpln, T, kF, kD);
    wconv_kernel<<<dim3(kD/64, kF/64), blk, 0, stream>>>(w2l, ffn_hi, ffn_lo, kF, kD);
    mfma_gemm<2,0,64><<<dim3(kD/64, T/128), blk, 0, stream>>>(
        fpln, nullptr, ffn_hi, ffn_lo, b2 + (size_t)l * kD, x, x, T, kD, kF);
  }

  ln_kernel<<<T, blk, 0, stream>>>(x, fa, fb, out);
}

// Round 3
// 1633.213 us; speedup vs baseline: 1.2323x; 1.0603x over previous
//
#include <hip/hip_runtime.h>
#include <math.h>
#include <stdint.h>

// Problem constants (match reference)
constexpr int kB = 2, kS = 2048, kD = 1024, kH = 16, kF = 4096, kL = 3;
constexpr int kDK = 64;
constexpr int kQKV = 3 * kD;            // fused QKV width 3072

typedef __attribute__((ext_vector_type(8))) short short8;
typedef __attribute__((ext_vector_type(4))) float floatx4;

// bf16 helpers (RNE pack, shift-unpack)
__device__ inline float bf2f(unsigned short u) {
  union { uint32_t i; float f; } v; v.i = (uint32_t)u << 16; return v.f;
}
__device__ inline unsigned short f2bf(float x) {
  union { float f; uint32_t i; } v; v.f = x;
  uint32_t r = v.i + 0x7fffu + ((v.i >> 16) & 1u);
  return (unsigned short)(r >> 16);
}

// async global->LDS DMA, 16B per lane; LDS dest = wave-uniform base + lane*16
__device__ inline void dma16(const void* g, void* l) {
  __builtin_amdgcn_global_load_lds(
      (const __attribute__((address_space(1))) unsigned int*)g,
      (__attribute__((address_space(3))) unsigned int*)l, 16, 0, 0);
}

// ---------------------------------------------------------------------------
// Embedding: x[b,s,:] = emb[tok]*sqrt(D) + pe[s,:]
// ---------------------------------------------------------------------------
__global__ __launch_bounds__(256) void embed_kernel(
    const int* __restrict__ tokens, const float* __restrict__ emb,
    const float* __restrict__ pe, float* __restrict__ x)
{
  int i = blockIdx.x;
  int s = i & (kS - 1);
  int tok = tokens[i];
  const float4* ep = (const float4*)(emb + (size_t)tok * kD);
  const float4* pp = (const float4*)(pe + (size_t)s * kD);
  float4* xp = (float4*)(x + (size_t)i * kD);
  int t = threadIdx.x;
  float4 e = ep[t], p = pp[t];
  xp[t] = make_float4(e.x*32.0f + p.x, e.y*32.0f + p.y,
                      e.z*32.0f + p.z, e.w*32.0f + p.w);
}

// ---------------------------------------------------------------------------
// LayerNorm (torch-style: Bessel std ddof=1, eps on std) -> fp32 out
// ---------------------------------------------------------------------------
__global__ __launch_bounds__(256) void ln_kernel(
    const float* __restrict__ x, const float* __restrict__ ga,
    const float* __restrict__ gb, float* __restrict__ out)
{
  int row = blockIdx.x;
  int t = threadIdx.x;
  int lane = t & 63, wid = t >> 6;
  const float4* xp = (const float4*)(x + (size_t)row * kD);
  float4 v = xp[t];
  float s = v.x + v.y + v.z + v.w;
  #pragma unroll
  for (int o = 32; o; o >>= 1) s += __shfl_xor(s, o);
  __shared__ float red[4];
  if (lane == 0) red[wid] = s;
  __syncthreads();
  float mean = (red[0] + red[1] + red[2] + red[3]) * (1.0f / 1024.0f);
  float4 d = make_float4(v.x - mean, v.y - mean, v.z - mean, v.w - mean);
  float ss = d.x*d.x + d.y*d.y + d.z*d.z + d.w*d.w;
  #pragma unroll
  for (int o = 32; o; o >>= 1) ss += __shfl_xor(ss, o);
  __syncthreads();
  if (lane == 0) red[wid] = ss;
  __syncthreads();
  float var = (red[0] + red[1] + red[2] + red[3]) * (1.0f / 1023.0f);
  float inv = 1.0f / (sqrtf(var) + 1e-6f);
  float4 a4 = ((const float4*)ga)[t];
  float4 b4 = ((const float4*)gb)[t];
  float4 o4;
  o4.x = a4.x * d.x * inv + b4.x;
  o4.y = a4.y * d.y * inv + b4.y;
  o4.z = a4.z * d.z * inv + b4.z;
  o4.w = a4.w * d.w * inv + b4.w;
  ((float4*)(out + (size_t)row * kD))[t] = o4;
}

// ---------------------------------------------------------------------------
// LayerNorm -> bf16 hi/lo planes (input to split-bf16 MFMA GEMMs)
// ---------------------------------------------------------------------------
__global__ __launch_bounds__(256) void ln_split_kernel(
    const float* __restrict__ x, const float* __restrict__ ga,
    const float* __restrict__ gb, unsigned short* __restrict__ hi,
    unsigned short* __restrict__ lo)
{
  int row = blockIdx.x;
  int t = threadIdx.x;
  int lane = t & 63, wid = t >> 6;
  const float4* xp = (const float4*)(x + (size_t)row * kD);
  float4 v = xp[t];
  float s = v.x + v.y + v.z + v.w;
  #pragma unroll
  for (int o = 32; o; o >>= 1) s += __shfl_xor(s, o);
  __shared__ float red[4];
  if (lane == 0) red[wid] = s;
  __syncthreads();
  float mean = (red[0] + red[1] + red[2] + red[3]) * (1.0f / 1024.0f);
  float4 d = make_float4(v.x - mean, v.y - mean, v.z - mean, v.w - mean);
  float ss = d.x*d.x + d.y*d.y + d.z*d.z + d.w*d.w;
  #pragma unroll
  for (int o = 32; o; o >>= 1) ss += __shfl_xor(ss, o);
  __syncthreads();
  if (lane == 0) red[wid] = ss;
  __syncthreads();
  float var = (red[0] + red[1] + red[2] + red[3]) * (1.0f / 1023.0f);
  float inv = 1.0f / (sqrtf(var) + 1e-6f);
  float4 a4 = ((const float4*)ga)[t];
  float4 b4 = ((const float4*)gb)[t];
  float o0 = a4.x * d.x * inv + b4.x;
  float o1 = a4.y * d.y * inv + b4.y;
  float o2 = a4.z * d.z * inv + b4.z;
  float o3 = a4.w * d.w * inv + b4.w;
  ushort4 h4, l4;
  h4.x = f2bf(o0); l4.x = f2bf(o0 - bf2f(h4.x));
  h4.y = f2bf(o1); l4.y = f2bf(o1 - bf2f(h4.y));
  h4.z = f2bf(o2); l4.z = f2bf(o2 - bf2f(h4.z));
  h4.w = f2bf(o3); l4.w = f2bf(o3 - bf2f(h4.w));
  *(ushort4*)&hi[(size_t)row * kD + 4*t] = h4;
  *(ushort4*)&lo[(size_t)row * kD + 4*t] = l4;
}

// ---------------------------------------------------------------------------
// Weight convert: W[K][N] fp32 -> transposed bf16 hi/lo planes Wt[N][K].
// ---------------------------------------------------------------------------
__global__ __launch_bounds__(256) void wconv_kernel(
    const float* __restrict__ W, unsigned short* __restrict__ hi,
    unsigned short* __restrict__ lo, int K, int N)
{
  __shared__ float tile[64][65];
  int n0 = blockIdx.x * 64, k0 = blockIdx.y * 64;
  int c = threadIdx.x & 63, r0 = threadIdx.x >> 6;
  #pragma unroll
  for (int p = 0; p < 16; ++p) {
    int r = r0 + 4 * p;
    tile[r][c] = W[(size_t)(k0 + r) * N + n0 + c];
  }
  __syncthreads();
  #pragma unroll
  for (int p = 0; p < 16; ++p) {
    int nn = r0 + 4 * p;
    float xv = tile[c][nn];                 // = W[k0+c][n0+nn]
    unsigned short h = f2bf(xv);
    size_t o = (size_t)(n0 + nn) * K + k0 + c;
    hi[o] = h;
    lo[o] = f2bf(xv - bf2f(h));
  }
}

// ---------------------------------------------------------------------------
// Split-bf16 MFMA GEMM v3.  A hi/lo [M][K] bf16; W hi/lo transposed [N][K].
// TERMS=3: Ahi*Whi + Ahi*Wlo + Alo*Whi.  TERMS=2: Ahi*(Whi+Wlo).
// BN=128: 128x128 tile, 4 waves of 64x64 (4x4 frags).
// BN=64:  128x64 tile,  4 waves of 64x32 (4x2 frags) — for narrow-N GEMMs
//         (N=1024): doubles the grid (512 blocks -> 2 blocks/CU) so the
//         vmcnt-drain barrier stall is hidden by cross-block overlap.
// Staging via global_load_lds width=16 (async DMA).
// Chunk-XOR swizzle applied on the global address side -> frag ds_read_b128
// hits 8 bank-groups x 2-way = conflict-free.
// OUTMODE 0: fp32 (+resid). 1: relu->bf16 plane. 2: bf16 plane.
// OUTMODE 3: fused-QKV special: cols<2048 -> bf16 qk [M][2048];
//            cols>=2048 -> bf16 V^T [(b*16+h)][dk=64][s=2048] via `resid` ptr.
// ---------------------------------------------------------------------------
template<int TERMS, int OUTMODE, int BN>
__global__ __launch_bounds__(256, 3) void mfma_gemm(
    const unsigned short* __restrict__ Ahi, const unsigned short* __restrict__ Alo,
    const unsigned short* __restrict__ Whi, const unsigned short* __restrict__ Wlo,
    const float* __restrict__ bias, const float* __restrict__ resid,
    void* __restrict__ out, int M, int N, int K)
{
  constexpr int NJ = (BN == 128) ? 4 : 2;   // N-frags per wave

  __shared__ unsigned short sAhi[128 * 32];
  __shared__ unsigned short sBhi[BN * 32];
  __shared__ unsigned short sBlo[BN * 32];
  __shared__ unsigned short sAlo[TERMS == 3 ? 128 * 32 : 64];

  int t = threadIdx.x;
  int lane = t & 63, wv = t >> 6;
  int wm, wn;
  if (BN == 128) { wm = (wv >> 1) * 64; wn = (wv & 1) * 64; }
  else           { wm = (wv & 1) * 64;  wn = (wv >> 1) * 32; }
  int lr = lane & 15, lq = lane >> 4;
  int m0 = blockIdx.y * 128, n0 = blockIdx.x * BN;

  // DMA lane mapping: wave-op W covers rows 16W..16W+15, lane l -> row
  // 16W+(l>>2), global chunk (l&3)^s(row), s = ((l>>2)^(l>>4))&3.
  int u = lane >> 2;
  int kq_g = (lane & 3) ^ ((u ^ (u >> 2)) & 3);
  // fragment-read swizzle: s depends only on row mod 16 (= lr)
  int swv = (lr ^ (lr >> 2)) & 3;

  floatx4 acc[4][NJ];
  #pragma unroll
  for (int i = 0; i < 4; ++i)
    #pragma unroll
    for (int j = 0; j < NJ; ++j) acc[i][j] = (floatx4){0.f, 0.f, 0.f, 0.f};

  for (int k0 = 0; k0 < K; k0 += 32) {
    __syncthreads();                         // prev iter's frag readers done
    #pragma unroll
    for (int p = 0; p < 2; ++p) {
      int W = 2 * wv + p;
      size_t ga = (size_t)(m0 + 16 * W + u) * K + k0 + 8 * kq_g;
      dma16(&Ahi[ga], &sAhi[W * 512]);
      if (TERMS == 3) dma16(&Alo[ga], &sAlo[W * 512]);
    }
    if (BN == 128) {
      #pragma unroll
      for (int p = 0; p < 2; ++p) {
        int W = 2 * wv + p;
        size_t gb = (size_t)(n0 + 16 * W + u) * K + k0 + 8 * kq_g;
        dma16(&Whi[gb], &sBhi[W * 512]);
        dma16(&Wlo[gb], &sBlo[W * 512]);
      }
    } else {
      int W = wv;
      size_t gb = (size_t)(n0 + 16 * W + u) * K + k0 + 8 * kq_g;
      dma16(&Whi[gb], &sBhi[W * 512]);
      dma16(&Wlo[gb], &sBlo[W * 512]);
    }
    __syncthreads();                         // drains vmcnt -> DMA visible

    short8 ah[4], bh[NJ];
    #pragma unroll
    for (int i = 0; i < 4; ++i)
      ah[i] = *(const short8*)&sAhi[(wm + 16*i + lr) * 32 + 8 * (lq ^ swv)];
    #pragma unroll
    for (int j = 0; j < NJ; ++j)
      bh[j] = *(const short8*)&sBhi[(wn + 16*j + lr) * 32 + 8 * (lq ^ swv)];
    #pragma unroll
    for (int i = 0; i < 4; ++i)
      #pragma unroll
      for (int j = 0; j < NJ; ++j)
        acc[i][j] = __builtin_amdgcn_mfma_f32_16x16x32_bf16(ah[i], bh[j], acc[i][j], 0, 0, 0);

    short8 bl[NJ];
    #pragma unroll
    for (int j = 0; j < NJ; ++j)
      bl[j] = *(const short8*)&sBlo[(wn + 16*j + lr) * 32 + 8 * (lq ^ swv)];
    #pragma unroll
    for (int i = 0; i < 4; ++i)
      #pragma unroll
      for (int j = 0; j < NJ; ++j)
        acc[i][j] = __builtin_amdgcn_mfma_f32_16x16x32_bf16(ah[i], bl[j], acc[i][j], 0, 0, 0);

    if (TERMS == 3) {
      short8 al[4];
      #pragma unroll
      for (int i = 0; i < 4; ++i)
        al[i] = *(const short8*)&sAlo[(wm + 16*i + lr) * 32 + 8 * (lq ^ swv)];
      #pragma unroll
      for (int i = 0; i < 4; ++i)
        #pragma unroll
        for (int j = 0; j < NJ; ++j)
          acc[i][j] = __builtin_amdgcn_mfma_f32_16x16x32_bf16(al[i], bh[j], acc[i][j], 0, 0, 0);
    }
  }

  if (OUTMODE == 3) {
    // fused-QKV epilogue: Q,K cols -> qk [M][2048]; V cols -> transposed vT.
    unsigned short* qk  = (unsigned short*)out;
    unsigned short* vTp = (unsigned short*)resid;   // aux output via resid slot
    #pragma unroll
    for (int i = 0; i < 4; ++i) {
      #pragma unroll
      for (int j = 0; j < NJ; ++j) {
        int col = n0 + wn + 16*j + lr;
        float bv = bias[col];
        int row0 = m0 + wm + 16*i + 4*lq;
        if (col < 2048) {
          #pragma unroll
          for (int r = 0; r < 4; ++r)
            qk[(size_t)(row0 + r) * 2048 + col] = f2bf(acc[i][j][r] + bv);
        } else {
          ushort4 w;
          w.x = f2bf(acc[i][j][0] + bv);
          w.y = f2bf(acc[i][j][1] + bv);
          w.z = f2bf(acc[i][j][2] + bv);
          w.w = f2bf(acc[i][j][3] + bv);
          int bb = row0 >> 11, s0 = row0 & 2047;
          int hh = (col - 2048) >> 6, dk = (col - 2048) & 63;
          *(ushort4*)&vTp[((size_t)((bb << 4) + hh) * 64 + dk) * 2048 + s0] = w;
        }
      }
    }
    return;
  }

  // epilogue: C/D layout col=lane&15, row=(lane>>4)*4+reg
  #pragma unroll
  for (int i = 0; i < 4; ++i) {
    #pragma unroll
    for (int j = 0; j < NJ; ++j) {
      int col = n0 + wn + 16*j + lr;
      float bv = bias[col];
      #pragma unroll
      for (int r = 0; r < 4; ++r) {
        int row = m0 + wm + 16*i + 4*lq + r;
        float val = acc[i][j][r] + bv;
        if (OUTMODE == 0) {
          if (resid) val += resid[(size_t)row * N + col];
          ((float*)out)[(size_t)row * N + col] = val;
        } else if (OUTMODE == 1) {
          ((unsigned short*)out)[(size_t)row * N + col] = f2bf(fmaxf(val, 0.f));
        } else {
          ((unsigned short*)out)[(size_t)row * N + col] = f2bf(val);
        }
      }
    }
  }
}

// ---------------------------------------------------------------------------
// MFMA flash attention v3.
//  - Q,K from qk [T][2048] (Q cols 0..1023, K cols 1024..2047), ld = 2048.
//  - V from pre-transposed vT [(b*16+h)][dk=64][s=2048] (GEMM OUTMODE 3).
//  - Staging via global_load_lds w=16, global-side chunk^row swizzle.
//  - Softmax restructured (VALU was the bottleneck: 43% busy, 32 dependent
//    shfl ops/tile):
//      * l-sum via MFMA against all-ones B-frag -> kills the 16-lane sum
//        reduce chain; denominator sums the same bf16 P as the numerator.
//      * defer-max (THR: log2 P <= 8): fast path skips max-reduce chain,
//        alf exps, and Oacc/lacc rescale. m tracked in raw score units,
//        msc = m * (0.125*log2e).
//      * P = exp2(fma(s, c, -msc)) — scale folded into exp2 constant.
//      * P->bf16 via v_cvt_pk_bf16_f32 (RNE), 2 cvt + 2 shr per row.
// ---------------------------------------------------------------------------
#define ASTR 72
#define CL2E 0.18033688011112042f   /* 0.125 * log2(e) */

__global__ __launch_bounds__(256, 4) void attn_kernel(
    const unsigned short* __restrict__ QKg, const unsigned short* __restrict__ vT,
    const int* __restrict__ mask, unsigned short* __restrict__ oHi,
    unsigned short* __restrict__ oLo)
{
  __shared__ unsigned short Qs[64 * 64];   // [q][d]  swizzled chunks
  __shared__ unsigned short Ks[64 * 64];   // [k][d]  swizzled chunks
  __shared__ unsigned short Vs[64 * 64];   // [d][k]  swizzled chunks
  __shared__ unsigned short Ps[64 * ASTR]; // [q][k]  padded stride

  int bi = blockIdx.x;
  int bh = bi & 31;                 // head-minor: same head -> same XCD
  int qt = bi >> 5;
  int h = bh & 15, b = bh >> 4;
  int q0 = qt * 64;
  int t = threadIdx.x;
  int lane = t & 63, wv = t >> 6;
  int lr = lane & 15, lq = lane >> 4;
  int wq = wv * 16;

  const size_t qbase = (size_t)b * kS * 2048 + (size_t)h * kDK;
  const size_t kbase = qbase + 1024;
  const size_t vbase = (size_t)(b * kH + h) * 64 * 2048;
  const size_t hout  = (size_t)b * kS * kD + (size_t)h * kDK;

  // stage Q (64 rows x 8 chunks), swizzle on global side
  #pragma unroll
  for (int p = 0; p < 2; ++p) {
    int idx = t + 256 * p;
    int row = idx >> 3, cg = (idx & 7) ^ (row & 7);
    dma16(&QKg[qbase + (size_t)(q0 + row) * 2048 + 8 * cg],
          &Qs[(p * 256 + wv * 64) * 8]);
  }

  short8 ones;
  #pragma unroll
  for (int e = 0; e < 8; ++e) ones[e] = (short)0x3F80;   // bf16 1.0

  floatx4 Oacc[4];
  floatx4 lacc = (floatx4){0.f, 0.f, 0.f, 0.f};
  float m_raw[4], msc[4];
  #pragma unroll
  for (int r = 0; r < 4; ++r) { m_raw[r] = -3.0e38f; msc[r] = -3.0e38f * CL2E; }
  #pragma unroll
  for (int j = 0; j < 4; ++j) Oacc[j] = (floatx4){0.f, 0.f, 0.f, 0.f};

  for (int k0 = 0; k0 < kS; k0 += 64) {
    __syncthreads();                      // prev tile's frag readers done
    #pragma unroll
    for (int p = 0; p < 2; ++p) {
      int idx = t + 256 * p;
      int row = idx >> 3, cg = (idx & 7) ^ (row & 7);
      dma16(&QKg[kbase + (size_t)(k0 + row) * 2048 + 8 * cg],
            &Ks[(p * 256 + wv * 64) * 8]);
      dma16(&vT[vbase + (size_t)row * 2048 + k0 + 8 * cg],
            &Vs[(p * 256 + wv * 64) * 8]);
    }
    int mv[4];
    #pragma unroll
    for (int j = 0; j < 4; ++j) mv[j] = mask[b * kS + k0 + 16*j + lr];
    __syncthreads();                      // drains vmcnt -> DMA visible

    floatx4 sac[4];
    #pragma unroll
    for (int j = 0; j < 4; ++j) sac[j] = (floatx4){0.f, 0.f, 0.f, 0.f};
    #pragma unroll
    for (int ks = 0; ks < 2; ++ks) {
      int cs = ((4 * ks + lq) ^ (lr & 7)) * 8;
      short8 af = *(const short8*)&Qs[(wq + lr) * 64 + cs];
      short8 bf[4];
      #pragma unroll
      for (int j = 0; j < 4; ++j)
        bf[j] = *(const short8*)&Ks[(16*j + lr) * 64 + cs];
      #pragma unroll
      for (int j = 0; j < 4; ++j)
        sac[j] = __builtin_amdgcn_mfma_f32_16x16x32_bf16(af, bf[j], sac[j], 0, 0, 0);
    }

    // mask (raw scores; masked -> -3e38 so exp2 underflows to 0)
    #pragma unroll
    for (int j = 0; j < 4; ++j)
      if (mv[j] == 0)
        #pragma unroll
        for (int r = 0; r < 4; ++r) sac[j][r] = -3.0e38f;

    // per-thread partial row max + defer-max test
    float pm[4];
    int ok = 1;
    #pragma unroll
    for (int r = 0; r < 4; ++r) {
      pm[r] = fmaxf(fmaxf(sac[0][r], sac[1][r]),
                    fmaxf(sac[2][r], sac[3][r]));
      ok &= (__builtin_fmaf(pm[r], CL2E, -msc[r]) <= 8.0f) ? 1 : 0;
    }
    if (!__all(ok)) {                     // slow path: real max update
      #pragma unroll
      for (int r = 0; r < 4; ++r) {
        float mx = pm[r];
        #pragma unroll
        for (int o = 1; o < 16; o <<= 1) mx = fmaxf(mx, __shfl_xor(mx, o));
        float newm = fmaxf(m_raw[r], mx);
        float nmsc = newm * CL2E;
        float alf = __builtin_exp2f(msc[r] - nmsc);
        m_raw[r] = newm; msc[r] = nmsc;
        lacc[r] *= alf;
        #pragma unroll
        for (int j = 0; j < 4; ++j) Oacc[j][r] *= alf;
      }
    }

    // P = exp2(c*s - msc), pack to bf16 via cvt_pk, scatter into Ps
    #pragma unroll
    for (int r = 0; r < 4; ++r) {
      float e0 = __builtin_exp2f(__builtin_fmaf(sac[0][r], CL2E, -msc[r]));
      float e1 = __builtin_exp2f(__builtin_fmaf(sac[1][r], CL2E, -msc[r]));
      float e2 = __builtin_exp2f(__builtin_fmaf(sac[2][r], CL2E, -msc[r]));
      float e3 = __builtin_exp2f(__builtin_fmaf(sac[3][r], CL2E, -msc[r]));
      uint32_t u01, u23;
      asm("v_cvt_pk_bf16_f32 %0, %1, %2" : "=v"(u01) : "v"(e0), "v"(e1));
      asm("v_cvt_pk_bf16_f32 %0, %1, %2" : "=v"(u23) : "v"(e2), "v"(e3));
      int row = wq + 4*lq + r;
      Ps[row * ASTR +      lr] = (unsigned short)u01;
      Ps[row * ASTR + 16 + lr] = (unsigned short)(u01 >> 16);
      Ps[row * ASTR + 32 + lr] = (unsigned short)u23;
      Ps[row * ASTR + 48 + lr] = (unsigned short)(u23 >> 16);
    }

    #pragma unroll
    for (int ks = 0; ks < 2; ++ks) {
      int cs = ((4 * ks + lq) ^ (lr & 7)) * 8;
      short8 pa = *(const short8*)&Ps[(wq + lr) * ASTR + 32*ks + 8*lq];
      lacc = __builtin_amdgcn_mfma_f32_16x16x32_bf16(pa, ones, lacc, 0, 0, 0);
      short8 vb[4];
      #pragma unroll
      for (int j = 0; j < 4; ++j)
        vb[j] = *(const short8*)&Vs[(16*j + lr) * 64 + cs];
      #pragma unroll
      for (int j = 0; j < 4; ++j)
        Oacc[j] = __builtin_amdgcn_mfma_f32_16x16x32_bf16(pa, vb[j], Oacc[j], 0, 0, 0);
    }
  }

  float inv[4];
  #pragma unroll
  for (int r = 0; r < 4; ++r) inv[r] = 1.0f / lacc[r];
  #pragma unroll
  for (int j = 0; j < 4; ++j)
    #pragma unroll
    for (int r = 0; r < 4; ++r) {
      int row = q0 + wq + 4*lq + r;
      float val = Oacc[j][r] * inv[r];
      unsigned short hv = f2bf(val);
      unsigned short lv = f2bf(val - bf2f(hv));
      size_t addr = hout + (size_t)row * kD + 16*j + lr;
      oHi[addr] = hv;
      oLo[addr] = lv;
    }
}

// ---------------------------------------------------------------------------
// Orchestration. Workspace byte layout (<= 96 MiB):
//   x      [ 0,16) fp32
//   hHi    [16,24)   hLo [24,32)                 bf16 activation planes
//   qk     [32,48)  bf16 [T][2048] Q|K           (attention phase)
//   vT     [48,56)  bf16 [32][64][2048] V^T      (attention phase)
//   biasqkv[56,56+12KB) fp32[3072]               (attention phase)
//   fpln   [32,64)  bf16 FFN plane               (FFN phase, aliases qk/vT)
//   Wbuf   [64,96): qkv_hi[64,70) qkv_lo[70,76) so_hi[76,78) so_lo[78,80)
//                   ffn_hi[80,88) ffn_lo[88,96)  (w1 then w2, rotating)
// ---------------------------------------------------------------------------
extern "C" void kernel_launch(void* const* d_in, const int* in_sizes, int n_in,
                              void* d_out, int out_size, void* d_ws, size_t ws_size,
                              hipStream_t stream) {
  const int*   tokens = (const int*)d_in[0];
  const int*   mask   = (const int*)d_in[1];
  const float* emb    = (const float*)d_in[2];
  const float* pe     = (const float*)d_in[3];
  const float* Wq     = (const float*)d_in[4];
  const float* bq     = (const float*)d_in[5];
  const float* Wk     = (const float*)d_in[6];
  const float* bk     = (const float*)d_in[7];
  const float* Wv     = (const float*)d_in[8];
  const float* bv     = (const float*)d_in[9];
  const float* Wo     = (const float*)d_in[10];
  const float* bo     = (const float*)d_in[11];
  const float* w1     = (const float*)d_in[12];
  const float* b1     = (const float*)d_in[13];
  const float* w2     = (const float*)d_in[14];
  const float* b2     = (const float*)d_in[15];
  const float* ln_a   = (const float*)d_in[16];
  const float* ln_b   = (const float*)d_in[17];
  const float* fa     = (const float*)d_in[18];
  const float* fb     = (const float*)d_in[19];
  float* out = (float*)d_out;
  char*  ws  = (char*)d_ws;

  const int T = kB * kS;                       // 4096 rows
  constexpr size_t MB = 1024 * 1024;

  float*          x     = (float*)(ws);
  unsigned short* hHi   = (unsigned short*)(ws + 16 * MB);
  unsigned short* hLo   = (unsigned short*)(ws + 24 * MB);
  unsigned short* qk    = (unsigned short*)(ws + 32 * MB);
  unsigned short* vT    = (unsigned short*)(ws + 48 * MB);
  float*          bqkv  = (float*)(ws + 56 * MB);
  unsigned short* fpln  = (unsigned short*)(ws + 32 * MB);  // aliases qk/vT
  char*           Wbuf  = ws + 64 * MB;

  unsigned short* qkv_hi = (unsigned short*)(Wbuf);            // [3072][1024]
  unsigned short* qkv_lo = (unsigned short*)(Wbuf + 6 * MB);
  unsigned short* so_hi  = (unsigned short*)(Wbuf + 12 * MB);
  unsigned short* so_lo  = (unsigned short*)(Wbuf + 14 * MB);
  unsigned short* ffn_hi = (unsigned short*)(Wbuf + 16 * MB);
  unsigned short* ffn_lo = (unsigned short*)(Wbuf + 24 * MB);

  dim3 blk(256);
  embed_kernel<<<T, blk, 0, stream>>>(tokens, emb, pe, x);

  for (int l = 0; l < kL; ++l) {
    const float* Wql = Wq + (size_t)l * kD * kD;
    const float* Wkl = Wk + (size_t)l * kD * kD;
    const float* Wvl = Wv + (size_t)l * kD * kD;
    const float* Wol = Wo + (size_t)l * kD * kD;
    const float* w1l = w1 + (size_t)l * kD * kF;
    const float* w2l = w2 + (size_t)l * kF * kD;

    // fused QKV weight planes: rows 0..1023 = Wq^T, 1024.. = Wk^T, 2048.. = Wv^T
    wconv_kernel<<<dim3(kD/64, kD/64), blk, 0, stream>>>(
        Wql, qkv_hi,                 qkv_lo,                 kD, kD);
    wconv_kernel<<<dim3(kD/64, kD/64), blk, 0, stream>>>(
        Wkl, qkv_hi + (size_t)kD*kD, qkv_lo + (size_t)kD*kD, kD, kD);
    wconv_kernel<<<dim3(kD/64, kD/64), blk, 0, stream>>>(
        Wvl, qkv_hi + (size_t)2*kD*kD, qkv_lo + (size_t)2*kD*kD, kD, kD);
    wconv_kernel<<<dim3(kD/64, kD/64), blk, 0, stream>>>(Wol, so_hi, so_lo, kD, kD);
    hipMemcpyAsync(bqkv,          bq + (size_t)l*kD, kD*4, hipMemcpyDeviceToDevice, stream);
    hipMemcpyAsync(bqkv + kD,     bk + (size_t)l*kD, kD*4, hipMemcpyDeviceToDevice, stream);
    hipMemcpyAsync(bqkv + 2*kD,   bv + (size_t)l*kD, kD*4, hipMemcpyDeviceToDevice, stream);

    // --- attention sublayer ---
    ln_split_kernel<<<T, blk, 0, stream>>>(x, ln_a + (size_t)l * 2 * kD,
                                           ln_b + (size_t)l * 2 * kD, hHi, hLo);
    mfma_gemm<3,3,128><<<dim3(kQKV/128, T/128), blk, 0, stream>>>(
        hHi, hLo, qkv_hi, qkv_lo, bqkv, (const float*)vT, qk, T, kQKV, kD);
    attn_kernel<<<kB * kH * (kS / 64), blk, 0, stream>>>(
        qk, vT, mask, hHi, hLo);
    mfma_gemm<3,0,64><<<dim3(kD/64, T/128), blk, 0, stream>>>(
        hHi, hLo, so_hi, so_lo, bo + (size_t)l * kD, x, x, T, kD, kD);

    // --- feed-forward sublayer ---
    ln_split_kernel<<<T, blk, 0, stream>>>(x, ln_a + (size_t)l * 2 * kD + kD,
                                           ln_b + (size_t)l * 2 * kD + kD, hHi, hLo);
    wconv_kernel<<<dim3(kF/64, kD/64), blk, 0, stream>>>(w1l, ffn_hi, ffn_lo, kD, kF);
    mfma_gemm<3,1,128><<<dim3(kF/128, T/128), blk, 0, stream>>>(
        hHi, hLo, ffn_hi, ffn_lo, b1 + (size_t)l * kF, nullptr, fpln, T, kF, kD);
    wconv_kernel<<<dim3(kD/64, kF/64), blk, 0, stream>>>(w2l, ffn_hi, ffn_lo, kF, kD);
    mfma_gemm<2,0,64><<<dim3(kD/64, T/128), blk, 0, stream>>>(
        fpln, nullptr, ffn_hi, ffn_lo, b2 + (size_t)l * kD, x, x, T, kD, kF);
  }

  ln_kernel<<<T, blk, 0, stream>>>(x, fa, fb, out);
}